// Round 3
// baseline (396.691 us; speedup 1.0000x reference)
//
#include <hip/hip_runtime.h>
#include <hip/hip_cooperative_groups.h>

namespace cg = cooperative_groups;

#define DEV_INLINE __device__ __forceinline__

// Problem dims (fixed by setup_inputs)
constexpr int B = 16, T = 4096, C = 512, K = 3;
constexpr int NC = 64;           // chunks along T
constexpr int L  = T / NC;       // 64 steps per chunk
constexpr int C4 = C / 4;        // 128 float4 lanes across channels
constexpr float EPS = 1e-4f;

// Single cooperative kernel, grid = B*NC = 1024 blocks x 128 threads (8 waves/CU,
// trivially co-resident on 256 CUs).
//
// Phase 1: stream x ONCE (nontemporal loads -> no L3 allocate); write the
//   zero-init local output out_local = mix . y_local (normal stores -> L3)
//   and the chunk-end carry states (6 MB ws).
// grid.sync()  (device barrier + fence; replaces a kernel drain + launch)
// Phase 2: block re-derives its chunk's incoming state E by scanning the
//   carries of chunks < i (parallel, redundant, cheap), then RMWs its OWN
//   chunk: out[j] += sum_k m_k a_k^(j+1) E_k. out_local is L2/L3-hot.
//
// HBM traffic = 134 MB x-read + 134 MB final out writeback = streaming minimum.

typedef float f4v __attribute__((ext_vector_type(4)));

DEV_INLINE float4 f4mul(float4 a, float4 b) {
  return make_float4(a.x * b.x, a.y * b.y, a.z * b.z, a.w * b.w);
}
DEV_INLINE float4 f4add(float4 a, float4 b) {
  return make_float4(a.x + b.x, a.y + b.y, a.z + b.z, a.w + b.w);
}
DEV_INLINE float4 f4fma(float4 a, float4 b, float4 c) {
  return make_float4(fmaf(a.x, b.x, c.x), fmaf(a.y, b.y, c.y),
                     fmaf(a.z, b.z, c.z), fmaf(a.w, b.w, c.w));
}
DEV_INLINE float4 f4onesub(float4 a) {
  return make_float4(1.f - a.x, 1.f - a.y, 1.f - a.z, 1.f - a.w);
}

DEV_INLINE float sig_clamp(float v) {
  float a = 1.0f / (1.0f + __expf(-v));
  return fminf(fmaxf(a, EPS), 1.0f - EPS);
}
DEV_INLINE float4 sig4(float4 v) {
  return make_float4(sig_clamp(v.x), sig_clamp(v.y), sig_clamp(v.z), sig_clamp(v.w));
}

DEV_INLINE void sm3(float l0, float l1, float l2, float& o0, float& o1, float& o2) {
  float mx = fmaxf(l0, fmaxf(l1, l2));
  float e0 = __expf(l0 - mx), e1 = __expf(l1 - mx), e2 = __expf(l2 - mx);
  float inv = 1.0f / (e0 + e1 + e2);
  o0 = e0 * inv; o1 = e1 * inv; o2 = e2 * inv;
}

// nontemporal float4 load: x is read exactly once -> don't allocate it in L3,
// so out_local owns the Infinity Cache for phase 2's RMW.
DEV_INLINE float4 nt_load(const float4* p) {
  f4v t = __builtin_nontemporal_load(reinterpret_cast<const f4v*>(p));
  float4 r; r.x = t.x; r.y = t.y; r.z = t.z; r.w = t.w; return r;
}

__global__ __launch_bounds__(128) void ema_fused(const float* __restrict__ x,
                                                 const float* __restrict__ logit_alpha,
                                                 const float* __restrict__ mix_logits,
                                                 float* __restrict__ carry_f,
                                                 float* __restrict__ out) {
  const int c4 = threadIdx.x;          // 0..C4-1
  const int bi = blockIdx.x;           // b*NC + chunk
  const int i  = bi & (NC - 1);
  const int b  = bi >> 6;              // NC = 64

  // per-channel tables (kept in registers across BOTH phases)
  const float4* la = (const float4*)logit_alpha;
  const float4 a0 = sig4(la[0 * C4 + c4]);
  const float4 a1 = sig4(la[1 * C4 + c4]);
  const float4 a2 = sig4(la[2 * C4 + c4]);
  const float4 b0 = f4onesub(a0), b1 = f4onesub(a1), b2 = f4onesub(a2);

  const float4* ml = (const float4*)mix_logits;   // [C][K] flattened
  const float4 q0 = ml[3 * c4 + 0];
  const float4 q1 = ml[3 * c4 + 1];
  const float4 q2 = ml[3 * c4 + 2];
  float4 m0, m1, m2;
  sm3(q0.x, q0.y, q0.z, m0.x, m1.x, m2.x);
  sm3(q0.w, q1.x, q1.y, m0.y, m1.y, m2.y);
  sm3(q1.z, q1.w, q2.x, m0.z, m1.z, m2.z);
  sm3(q2.y, q2.z, q2.w, m0.w, m1.w, m2.w);

  const float4* xb = (const float4*)x + (size_t)bi * L * C4 + c4;
  float4*       ob = (float4*)out     + (size_t)bi * L * C4 + c4;

  // ---------------- phase 1: local (zero-init) pass, x streamed once ----------------
  float4 y0, y1, y2;
  int jstart;
  if (i == 0) {
    // chunk 0: y[0] = x[0] exactly -> out_local is FINAL for this chunk
    float4 x0 = nt_load(&xb[0]);
    y0 = x0; y1 = x0; y2 = x0;
    ob[0] = f4fma(m0, y0, f4fma(m1, y1, f4mul(m2, y2)));
    jstart = 1;
  } else {
    y0 = make_float4(0.f, 0.f, 0.f, 0.f);
    y1 = y0; y2 = y0;
    jstart = 0;
  }

  #pragma unroll 4
  for (int j = jstart; j < L; ++j) {
    float4 xv = nt_load(&xb[(size_t)j * C4]);
    y0 = f4fma(a0, y0, f4mul(b0, xv));
    y1 = f4fma(a1, y1, f4mul(b1, xv));
    y2 = f4fma(a2, y2, f4mul(b2, xv));
    ob[(size_t)j * C4] = f4fma(m0, y0, f4fma(m1, y1, f4mul(m2, y2)));  // normal store -> L3
  }

  {
    float4* carry = (float4*)carry_f;
    const size_t cb = (size_t)bi * (K * C4) + c4;
    carry[cb + 0 * C4] = y0;
    carry[cb + 1 * C4] = y1;
    carry[cb + 2 * C4] = y2;
  }

  // ---------------- device-wide barrier (fence included) ----------------
  cg::this_grid().sync();

  if (i == 0) return;   // chunk 0 already final (no further syncs below)

  // ---------------- phase 2: carry-scan + additive correction RMW ----------------
  // A = a^L via 6 squarings (L = 64)
  float4 A0 = a0, A1 = a1, A2 = a2;
  #pragma unroll
  for (int s = 0; s < 6; ++s) { A0 = f4mul(A0, A0); A1 = f4mul(A1, A1); A2 = f4mul(A2, A2); }

  // incoming state E for chunk i: E_0 = s_0 (exact x0-init chunk), E_j = A*E_{j-1} + s_j
  const size_t stride = (size_t)K * C4;
  const float4* cbp = (const float4*)carry_f + (size_t)b * NC * stride + c4;
  float4 E0 = cbp[0 * C4];
  float4 E1 = cbp[1 * C4];
  float4 E2 = cbp[2 * C4];
  #pragma unroll 4
  for (int j = 1; j < i; ++j) {
    const float4* cj = cbp + (size_t)j * stride;
    E0 = f4fma(A0, E0, cj[0 * C4]);
    E1 = f4fma(A1, E1, cj[1 * C4]);
    E2 = f4fma(A2, E2, cj[2 * C4]);
  }

  // g_k = m_k * E_k ; corr_j = sum_k a_k^(j+1) * g_k
  const float4 g0 = f4mul(m0, E0);
  const float4 g1 = f4mul(m1, E1);
  const float4 g2 = f4mul(m2, E2);
  float4 p0 = a0, p1 = a1, p2 = a2;

  #pragma unroll 4
  for (int j = 0; j < L; ++j) {
    float4 corr = f4fma(p0, g0, f4fma(p1, g1, f4mul(p2, g2)));
    float4 o = ob[(size_t)j * C4];       // L2/L3-hot (this block wrote it)
    ob[(size_t)j * C4] = f4add(o, corr); // normal store: overwrites dirty line, one HBM writeback
    p0 = f4mul(p0, a0);
    p1 = f4mul(p1, a1);
    p2 = f4mul(p2, a2);
  }
}

extern "C" void kernel_launch(void* const* d_in, const int* in_sizes, int n_in,
                              void* d_out, int out_size, void* d_ws, size_t ws_size,
                              hipStream_t stream) {
  const float* x           = (const float*)d_in[0];
  const float* logit_alpha = (const float*)d_in[1];
  const float* mix_logits  = (const float*)d_in[2];
  float* out = (float*)d_out;
  float* ws  = (float*)d_ws;

  void* args[] = {(void*)&x, (void*)&logit_alpha, (void*)&mix_logits,
                  (void*)&ws, (void*)&out};
  hipLaunchCooperativeKernel((const void*)ema_fused, dim3(B * NC), dim3(128),
                             args, 0, stream);
}

// Round 4
// 299.369 us; speedup vs baseline: 1.3251x; 1.3251x over previous
//
#include <hip/hip_runtime.h>

#define DEV_INLINE __device__ __forceinline__

// Problem dims (fixed by setup_inputs)
constexpr int B = 16, T = 4096, C = 512, K = 3;
constexpr int NC = 128;          // chunks along T (parallelism knob: 2048 blocks, 4 waves/SIMD)
constexpr int L  = T / NC;       // 32 steps per chunk
constexpr int C4 = C / 4;        // 128 float4 lanes across channels
constexpr float EPS = 1e-4f;

// ws layout (floats): carry[b][chunk][k][c4] local-suffix states (12.6 MB)
//
// K1: per-chunk zero-init local suffix over x (normal loads -> x allocates in the
//     256 MB Infinity Cache), writes chunk-end states to carry.
// K2: re-derives chunk i's incoming state E by scanning carries of chunks < i
//     (parallel redundant scan, L2/L3-served), re-runs the exact recurrence over
//     x (L3 hits) and writes out with NONTEMPORAL stores so the 134 MB output
//     stream does not evict x from L3 mid-kernel.
// HBM traffic = 134 MB x (K1) + 134 MB out (K2) = streaming minimum.

typedef float f4v __attribute__((ext_vector_type(4)));

DEV_INLINE float4 f4mul(float4 a, float4 b) {
  return make_float4(a.x * b.x, a.y * b.y, a.z * b.z, a.w * b.w);
}
DEV_INLINE float4 f4fma(float4 a, float4 b, float4 c) {
  return make_float4(fmaf(a.x, b.x, c.x), fmaf(a.y, b.y, c.y),
                     fmaf(a.z, b.z, c.z), fmaf(a.w, b.w, c.w));
}
DEV_INLINE float4 f4onesub(float4 a) {
  return make_float4(1.f - a.x, 1.f - a.y, 1.f - a.z, 1.f - a.w);
}

DEV_INLINE float sig_clamp(float v) {
  float a = 1.0f / (1.0f + __expf(-v));
  return fminf(fmaxf(a, EPS), 1.0f - EPS);
}
DEV_INLINE float4 sig4(float4 v) {
  return make_float4(sig_clamp(v.x), sig_clamp(v.y), sig_clamp(v.z), sig_clamp(v.w));
}

DEV_INLINE void sm3(float l0, float l1, float l2, float& o0, float& o1, float& o2) {
  float mx = fmaxf(l0, fmaxf(l1, l2));
  float e0 = __expf(l0 - mx), e1 = __expf(l1 - mx), e2 = __expf(l2 - mx);
  float inv = 1.0f / (e0 + e1 + e2);
  o0 = e0 * inv; o1 = e1 * inv; o2 = e2 * inv;
}

// nontemporal float4 store: out is write-once streaming; nt keeps it from
// evicting x out of the Infinity Cache while K2 is still reading x.
DEV_INLINE void nt_store(float4* p, float4 v) {
  f4v t; t.x = v.x; t.y = v.y; t.z = v.z; t.w = v.w;
  __builtin_nontemporal_store(t, reinterpret_cast<f4v*>(p));
}

// ---------------- K1: per-chunk local suffix (zero-init EMA) ----------------
__global__ __launch_bounds__(128) void ema_k1(const float* __restrict__ x,
                                              const float* __restrict__ logit_alpha,
                                              float* __restrict__ carry_f) {
  const int c4 = threadIdx.x;          // 0..C4-1
  const int bi = blockIdx.x;           // b*NC + chunk
  const int i  = bi & (NC - 1);

  const float4* la = (const float4*)logit_alpha;
  const float4 a0 = sig4(la[0 * C4 + c4]);
  const float4 a1 = sig4(la[1 * C4 + c4]);
  const float4 a2 = sig4(la[2 * C4 + c4]);
  const float4 b0 = f4onesub(a0), b1 = f4onesub(a1), b2 = f4onesub(a2);

  const float4* xb = (const float4*)x + (size_t)bi * L * C4 + c4;

  float4 y0, y1, y2;
  int jstart;
  if (i == 0) {
    // chunk 0: y[0] = x[0] exactly (no incoming state)
    float4 x0 = xb[0];
    y0 = x0; y1 = x0; y2 = x0;
    jstart = 1;
  } else {
    y0 = make_float4(0.f, 0.f, 0.f, 0.f);
    y1 = y0; y2 = y0;
    jstart = 0;
  }

  #pragma unroll 8
  for (int j = jstart; j < L; ++j) {
    float4 xv = xb[(size_t)j * C4];
    y0 = f4fma(a0, y0, f4mul(b0, xv));
    y1 = f4fma(a1, y1, f4mul(b1, xv));
    y2 = f4fma(a2, y2, f4mul(b2, xv));
  }

  float4* carry = (float4*)carry_f;
  const size_t cb = (size_t)bi * (K * C4) + c4;
  carry[cb + 0 * C4] = y0;
  carry[cb + 1 * C4] = y1;
  carry[cb + 2 * C4] = y2;
}

// ---------------- K2: carry-scan + exact recurrence + mix, streamed out ----------------
__global__ __launch_bounds__(128) void ema_k2(const float* __restrict__ x,
                                              const float* __restrict__ logit_alpha,
                                              const float* __restrict__ mix_logits,
                                              const float* __restrict__ carry_f,
                                              float* __restrict__ out) {
  const int c4 = threadIdx.x;
  const int bi = blockIdx.x;
  const int i  = bi & (NC - 1);
  const int b  = bi / NC;

  const float4* la = (const float4*)logit_alpha;
  const float4 a0 = sig4(la[0 * C4 + c4]);
  const float4 a1 = sig4(la[1 * C4 + c4]);
  const float4 a2 = sig4(la[2 * C4 + c4]);
  const float4 b0 = f4onesub(a0), b1 = f4onesub(a1), b2 = f4onesub(a2);

  // mix softmax: channels 4*c4 .. 4*c4+3; mix_logits is [C][K], 12 floats/thread
  const float4* ml = (const float4*)mix_logits;
  const float4 q0 = ml[3 * c4 + 0];
  const float4 q1 = ml[3 * c4 + 1];
  const float4 q2 = ml[3 * c4 + 2];
  float4 m0, m1, m2;
  sm3(q0.x, q0.y, q0.z, m0.x, m1.x, m2.x);
  sm3(q0.w, q1.x, q1.y, m0.y, m1.y, m2.y);
  sm3(q1.z, q1.w, q2.x, m0.z, m1.z, m2.z);
  sm3(q2.y, q2.z, q2.w, m0.w, m1.w, m2.w);

  const float4* xb = (const float4*)x + (size_t)bi * L * C4 + c4;
  float4*       ob = (float4*)out     + (size_t)bi * L * C4 + c4;

  float4 y0, y1, y2;
  int jstart;
  if (i == 0) {
    float4 x0 = xb[0];
    y0 = x0; y1 = x0; y2 = x0;
    nt_store(&ob[0], f4fma(m0, y0, f4fma(m1, y1, f4mul(m2, y2))));
    jstart = 1;
  } else {
    // A = a^L via 5 squarings (L = 32)
    float4 A0 = a0, A1 = a1, A2 = a2;
    #pragma unroll
    for (int s = 0; s < 5; ++s) { A0 = f4mul(A0, A0); A1 = f4mul(A1, A1); A2 = f4mul(A2, A2); }

    // incoming state for chunk i: E_0 = s_0 (x0-init chunk, exact), E_j = A*E_{j-1} + s_j
    const size_t stride = (size_t)K * C4;
    const float4* cb = (const float4*)carry_f + (size_t)b * NC * stride + c4;
    y0 = cb[0 * C4];
    y1 = cb[1 * C4];
    y2 = cb[2 * C4];
    #pragma unroll 4
    for (int j = 1; j < i; ++j) {
      const float4* cj = cb + (size_t)j * stride;
      y0 = f4fma(A0, y0, cj[0 * C4]);
      y1 = f4fma(A1, y1, cj[1 * C4]);
      y2 = f4fma(A2, y2, cj[2 * C4]);
    }
    jstart = 0;
  }

  #pragma unroll 8
  for (int j = jstart; j < L; ++j) {
    float4 xv = xb[(size_t)j * C4];     // L3-resident (K1 just streamed x through L3)
    y0 = f4fma(a0, y0, f4mul(b0, xv));
    y1 = f4fma(a1, y1, f4mul(b1, xv));
    y2 = f4fma(a2, y2, f4mul(b2, xv));
    nt_store(&ob[(size_t)j * C4], f4fma(m0, y0, f4fma(m1, y1, f4mul(m2, y2))));
  }
}

extern "C" void kernel_launch(void* const* d_in, const int* in_sizes, int n_in,
                              void* d_out, int out_size, void* d_ws, size_t ws_size,
                              hipStream_t stream) {
  const float* x           = (const float*)d_in[0];
  const float* logit_alpha = (const float*)d_in[1];
  const float* mix_logits  = (const float*)d_in[2];
  float* out = (float*)d_out;
  float* ws  = (float*)d_ws;

  ema_k1<<<B * NC, 128, 0, stream>>>(x, logit_alpha, ws);
  ema_k2<<<B * NC, 128, 0, stream>>>(x, logit_alpha, mix_logits, ws, out);
}